// Round 6
// baseline (81.775 us; speedup 1.0000x reference)
//
#include <hip/hip_runtime.h>

// SelfAttentionHead: B=16, T=1024, C=768, H=64, fp32 in/out, causal softmax.
// wtrans: W -> Wt[192][768] f16.
// proj:   barrier-free, LDS-free BM=16 GEMM; A-frag via ds_bpermute lane
//         permutation; x/Wt prefetched 2-deep; 1024 blocks x 4 waves.
// attn:   split-KV flash attention. Each wave = (16 q-rows, <=4 KV tiles);
//         unnormalized partials (O, m, l) to ws; LSE-combine kernel merges.

typedef _Float16 half8 __attribute__((ext_vector_type(8)));
typedef _Float16 half4 __attribute__((ext_vector_type(4)));
typedef float float4v __attribute__((ext_vector_type(4)));

#define NB   16
#define NT   1024
#define NC   768
#define NH   64

// ---------------------------------------------------------------------------
// Wt[m*64+col][k] = Wm[k][col], m in {0:Q, 1:K, 2:V}. Grid (48,3) x 256.
// ---------------------------------------------------------------------------
__global__ __launch_bounds__(256) void wtrans_kernel(
    const float* __restrict__ Wq, const float* __restrict__ Wk,
    const float* __restrict__ Wv, _Float16* __restrict__ Wt)
{
    __shared__ float tile[16][68];
    const int m = blockIdx.y;
    const float* W = (m == 0) ? Wq : (m == 1) ? Wk : Wv;
    const int s = blockIdx.x;
    const int t = threadIdx.x;
    {
        const int kr = t >> 4, c4 = (t & 15) * 4;
        float4v v = *(const float4v*)(W + (size_t)(s * 16 + kr) * NH + c4);
        tile[kr][c4 + 0] = v[0]; tile[kr][c4 + 1] = v[1];
        tile[kr][c4 + 2] = v[2]; tile[kr][c4 + 3] = v[3];
    }
    __syncthreads();
    const int col = t >> 2, j = t & 3;
    half4 h;
#pragma unroll
    for (int i = 0; i < 4; ++i) h[i] = (_Float16)tile[j * 4 + i][col];
    *(half4*)(Wt + (size_t)(m * 64 + col) * NC + s * 16 + j * 4) = h;
}

// ---------------------------------------------------------------------------
// proj: grid 1024 x 256 thr (4 waves, no LDS, no barriers). Block: 16 rows.
// Wave wid owns cols wid*48..+48 (3 n-frags). A-frag: lane loads 8 consecutive
// f32 of row (lane>>2), k-chunk (lane&3)*8; bpermute from lane 4*l15+lhi gives
// MFMA A layout (row=l15, k=lhi*8..+8).
// ---------------------------------------------------------------------------
__global__ __launch_bounds__(256) void proj_kernel(
    const float* __restrict__ x, const _Float16* __restrict__ Wt,
    _Float16* __restrict__ Qb, _Float16* __restrict__ Kb,
    _Float16* __restrict__ Vt)
{
    const int t = threadIdx.x, wid = t >> 6, lane = t & 63;
    const int l15 = lane & 15, lhi = lane >> 4;
    const int m0 = blockIdx.x * 16;
    const int gcol0 = wid * 48;

    const float*    xsrc  = x  + (size_t)(m0 + (lane >> 2)) * NC + (lane & 3) * 8;
    const _Float16* wbase = Wt + (size_t)(gcol0 + l15) * NC + lhi * 8;
    const int bpidx = ((l15 << 2) | lhi) << 2;   // byte index for ds_bpermute

    float4v acc[3];
#pragma unroll
    for (int j = 0; j < 3; ++j) acc[j] = (float4v){0.f, 0.f, 0.f, 0.f};

    // 2-deep register prefetch
    float4v gx0[2], gx1[2];
    half8 bw[2][3];
#pragma unroll
    for (int p = 0; p < 2; ++p) {
        gx0[p] = *(const float4v*)(xsrc + p * 32);
        gx1[p] = *(const float4v*)(xsrc + p * 32 + 4);
#pragma unroll
        for (int nf = 0; nf < 3; ++nf)
            bw[p][nf] = *(const half8*)(wbase + (size_t)nf * 16 * NC + p * 32);
    }

#pragma unroll
    for (int kc = 0; kc < 24; ++kc) {
        const int cur = kc & 1;
        // consume current into locals
        float4v c0 = gx0[cur], c1 = gx1[cur];
        half8 b0 = bw[cur][0], b1 = bw[cur][1], b2 = bw[cur][2];
        // refill slot with kc+2
        if (kc + 2 < 24) {
            gx0[cur] = *(const float4v*)(xsrc + (kc + 2) * 32);
            gx1[cur] = *(const float4v*)(xsrc + (kc + 2) * 32 + 4);
#pragma unroll
            for (int nf = 0; nf < 3; ++nf)
                bw[cur][nf] = *(const half8*)(wbase + (size_t)nf * 16 * NC
                                              + (kc + 2) * 32);
        }
        // convert staged f32 -> f16
        union { unsigned int u[4]; half8 h; } S, P;
        S.h[0] = (_Float16)c0[0]; S.h[1] = (_Float16)c0[1];
        S.h[2] = (_Float16)c0[2]; S.h[3] = (_Float16)c0[3];
        S.h[4] = (_Float16)c1[0]; S.h[5] = (_Float16)c1[1];
        S.h[6] = (_Float16)c1[2]; S.h[7] = (_Float16)c1[3];
        // lane permutation -> A fragment
#pragma unroll
        for (int d = 0; d < 4; ++d)
            P.u[d] = (unsigned int)__builtin_amdgcn_ds_bpermute(bpidx, (int)S.u[d]);
        const half8 af = P.h;
        acc[0] = __builtin_amdgcn_mfma_f32_16x16x32_f16(af, b0, acc[0], 0, 0, 0);
        acc[1] = __builtin_amdgcn_mfma_f32_16x16x32_f16(af, b1, acc[1], 0, 0, 0);
        acc[2] = __builtin_amdgcn_mfma_f32_16x16x32_f16(af, b2, acc[2], 0, 0, 0);
    }

#pragma unroll
    for (int nf = 0; nf < 3; ++nf) {
        const int gc  = gcol0 + nf * 16;
        const int sel = gc >> 6;
        const int col = (gc & 63) + l15;
        const int row0 = m0 + lhi * 4;
        if (sel == 2) {
            const int bb = row0 >> 10, tt = row0 & 1023;
            half4 h;
#pragma unroll
            for (int r = 0; r < 4; ++r) h[r] = (_Float16)acc[nf][r];
            *(half4*)(Vt + ((size_t)(bb * 64 + col)) * NT + tt) = h;
        } else {
            _Float16* D = (sel == 0) ? Qb : Kb;
#pragma unroll
            for (int r = 0; r < 4; ++r)
                D[(size_t)(row0 + r) * NH + col] = (_Float16)acc[nf][r];
        }
    }
}

// ---------------------------------------------------------------------------
// attn partial: grid (160, 16) x 64 thr (1 wave). Block i -> (qw, chunk c);
// chunk covers KV tiles [c*4, min(c*4+4, nt)), nt = qw/4+1. Writes
// unnormalized O + (m, l) partials. Swapped QK^T, in-register softmax.
// ---------------------------------------------------------------------------
__global__ __launch_bounds__(64) void attn_part_kernel(
    const _Float16* __restrict__ Qb, const _Float16* __restrict__ Kb,
    const _Float16* __restrict__ Vt, float* __restrict__ partO,
    float* __restrict__ partML)
{
    const int lane = threadIdx.x;
    const int l15 = lane & 15, lhi = lane >> 4;
    const int b = blockIdx.y;
    const int i = blockIdx.x;
    int qw, c;
    if (i < 16)      { qw = i;                          c = 0; }
    else if (i < 48) { int j = i - 16; qw = 16 + (j >> 1); c = j & 1; }
    else if (i < 96) { int j = i - 48; int q3 = j / 3;  qw = 32 + q3; c = j - 3 * q3; }
    else             { int j = i - 96; qw = 48 + (j >> 2); c = j & 3; }

    const int q0 = qw * 16;
    const int nt = (q0 >> 6) + 1;
    const int t0 = c * 4;
    const int t1 = min(t0 + 4, nt);
    const int qrel = (q0 & 63) + l15;

    const _Float16* qsrc = Qb + ((size_t)(b * NT + q0 + l15)) * NH + lhi * 8;
    const half8 aq0 = *(const half8*)qsrc;
    const half8 aq1 = *(const half8*)(qsrc + 32);

    const _Float16* kptr = Kb + ((size_t)(b * NT + l15)) * NH + lhi * 8;
    const _Float16* vptr = Vt + ((size_t)(b * 64 + l15)) * NT + lhi * 8;

    float4v o[4];
#pragma unroll
    for (int nf = 0; nf < 4; ++nf) o[nf] = (float4v){0.f, 0.f, 0.f, 0.f};
    float m2 = -1e30f, lsum = 0.f;

    auto LOADK = [&](half8 (&bk)[8], int jt) {
#pragma unroll
        for (int kf = 0; kf < 4; ++kf)
#pragma unroll
            for (int ch = 0; ch < 2; ++ch)
                bk[kf * 2 + ch] = *(const half8*)(kptr
                    + ((size_t)(jt * 64 + kf * 16)) * NH + ch * 32);
    };

    auto STEP = [&](const half8 (&bk)[8], int jt, bool last) {
        half8 bv[8];
#pragma unroll
        for (int ks = 0; ks < 2; ++ks)
#pragma unroll
            for (int nf = 0; nf < 4; ++nf)
                bv[ks * 4 + nf] = *(const half8*)(vptr + (size_t)nf * 16 * NT
                                                  + jt * 64 + ks * 32);

        float4v sT[4];
#pragma unroll
        for (int kf = 0; kf < 4; ++kf) {
            float4v sv = (float4v){0.f, 0.f, 0.f, 0.f};
            sv = __builtin_amdgcn_mfma_f32_16x16x32_f16(bk[kf * 2 + 0], aq0, sv, 0, 0, 0);
            sv = __builtin_amdgcn_mfma_f32_16x16x32_f16(bk[kf * 2 + 1], aq1, sv, 0, 0, 0);
            sT[kf] = sv;
        }

        const float SC = 0.18033688f;   // 0.125 * log2(e)
        float p[4][4];
        float mt = -1e30f;
#pragma unroll
        for (int kf = 0; kf < 4; ++kf)
#pragma unroll
            for (int r = 0; r < 4; ++r) {
                float v = sT[kf][r] * SC;
                if (last) {
                    const int kpos = kf * 16 + lhi * 4 + r;
                    if (kpos > qrel) v = -1e30f;
                }
                p[kf][r] = v;
                mt = fmaxf(mt, v);
            }
        mt = fmaxf(mt, __shfl_xor(mt, 16));
        mt = fmaxf(mt, __shfl_xor(mt, 32));

        const float mnew = fmaxf(m2, mt);
        const float esc  = exp2f(m2 - mnew);
        float ps = 0.f;
#pragma unroll
        for (int kf = 0; kf < 4; ++kf)
#pragma unroll
            for (int r = 0; r < 4; ++r) {
                const float e = exp2f(p[kf][r] - mnew);
                p[kf][r] = e;
                ps += e;
            }
        ps += __shfl_xor(ps, 16);
        ps += __shfl_xor(ps, 32);
        lsum = lsum * esc + ps;
        m2 = mnew;

        float er[4];
#pragma unroll
        for (int r = 0; r < 4; ++r) er[r] = __shfl(esc, lhi * 4 + r);
#pragma unroll
        for (int nf = 0; nf < 4; ++nf)
#pragma unroll
            for (int r = 0; r < 4; ++r) o[nf][r] *= er[r];

        unsigned int pk[4][2];
#pragma unroll
        for (int kf = 0; kf < 4; ++kf)
#pragma unroll
            for (int pr = 0; pr < 2; ++pr) {
                auto h2 = __builtin_amdgcn_cvt_pkrtz(p[kf][2 * pr], p[kf][2 * pr + 1]);
                pk[kf][pr] = __builtin_bit_cast(unsigned int, h2);
            }

        const int sb = l15 + ((lhi & 1) * 2) * 16;
        const bool hi = (lhi >> 1) != 0;
#pragma unroll
        for (int ks = 0; ks < 2; ++ks) {
            unsigned int w[4];
#pragma unroll
            for (int m = 0; m < 4; ++m) {
                const int L = sb + ((m >> 1) << 4);
                const unsigned int wA = (unsigned int)__shfl((int)pk[2 * ks + 0][m & 1], L);
                const unsigned int wB = (unsigned int)__shfl((int)pk[2 * ks + 1][m & 1], L);
                w[m] = hi ? wB : wA;
            }
            union { unsigned int u[4]; half8 h; } cvt;
            cvt.u[0] = w[0]; cvt.u[1] = w[1]; cvt.u[2] = w[2]; cvt.u[3] = w[3];
            const half8 pa = cvt.h;
#pragma unroll
            for (int nf = 0; nf < 4; ++nf)
                o[nf] = __builtin_amdgcn_mfma_f32_16x16x32_f16(pa, bv[ks * 4 + nf],
                                                               o[nf], 0, 0, 0);
        }
    };

    half8 kA[8], kB[8];
    LOADK(kA, t0);
    int jt = t0;
    while (true) {
        if (jt + 1 < t1) LOADK(kB, jt + 1);
        STEP(kA, jt, jt == nt - 1);
        ++jt; if (jt == t1) break;
        if (jt + 1 < t1) LOADK(kA, jt + 1);
        STEP(kB, jt, jt == nt - 1);
        ++jt; if (jt == t1) break;
    }

    // write partials (unnormalized)
    const size_t base = (size_t)((b * 64 + qw) * 4 + c);
#pragma unroll
    for (int nf = 0; nf < 4; ++nf) {
        float4v v = o[nf];
        *(float4v*)(partO + (base * 4 + nf) * 256 + lane * 4) = v;
    }
    if (lhi == 0) {
        partML[base * 32 + l15 * 2 + 0] = m2;
        partML[base * 32 + l15 * 2 + 1] = lsum;
    }
}

// ---------------------------------------------------------------------------
// combine: grid (64, 16) x 64 thr. Merge <=4 partials per q-group (LSE merge),
// normalize, write fp32 out.
// ---------------------------------------------------------------------------
__global__ __launch_bounds__(64) void attn_comb_kernel(
    const float* __restrict__ partO, const float* __restrict__ partML,
    float* __restrict__ out)
{
    const int lane = threadIdx.x;
    const int l15 = lane & 15, lhi = lane >> 4;
    const int qw = blockIdx.x, b = blockIdx.y;
    const int nch = (qw >> 4) + 1;
    const size_t gbase = (size_t)(b * 64 + qw) * 4;

    float mc[4][4], lc[4][4];   // [chunk][r] — static indexing via full unroll
    float M[4];
#pragma unroll
    for (int r = 0; r < 4; ++r) M[r] = -1e30f;
#pragma unroll
    for (int cc = 0; cc < 4; ++cc) {
        if (cc < nch) {
#pragma unroll
            for (int r = 0; r < 4; ++r) {
                const int row = lhi * 4 + r;
                mc[cc][r] = partML[(gbase + cc) * 32 + row * 2 + 0];
                lc[cc][r] = partML[(gbase + cc) * 32 + row * 2 + 1];
                M[r] = fmaxf(M[r], mc[cc][r]);
            }
        }
    }
    float sc[4][4], L[4];
#pragma unroll
    for (int r = 0; r < 4; ++r) L[r] = 0.f;
#pragma unroll
    for (int cc = 0; cc < 4; ++cc) {
        if (cc < nch) {
#pragma unroll
            for (int r = 0; r < 4; ++r) {
                sc[cc][r] = exp2f(mc[cc][r] - M[r]);
                L[r] += lc[cc][r] * sc[cc][r];
            }
        }
    }
    float linv[4];
#pragma unroll
    for (int r = 0; r < 4; ++r) linv[r] = 1.f / L[r];

#pragma unroll
    for (int nf = 0; nf < 4; ++nf) {
        float acc[4] = {0.f, 0.f, 0.f, 0.f};
#pragma unroll
        for (int cc = 0; cc < 4; ++cc) {
            if (cc < nch) {
                float4v v = *(const float4v*)(partO + (gbase + cc) * 1024
                                              + nf * 256 + lane * 4);
#pragma unroll
                for (int r = 0; r < 4; ++r) acc[r] += v[r] * sc[cc][r];
            }
        }
#pragma unroll
        for (int r = 0; r < 4; ++r) {
            const int row = qw * 16 + lhi * 4 + r;
            out[((size_t)(b * NT + row)) * NH + nf * 16 + l15] = acc[r] * linv[r];
        }
    }
}

extern "C" void kernel_launch(void* const* d_in, const int* in_sizes, int n_in,
                              void* d_out, int out_size, void* d_ws, size_t ws_size,
                              hipStream_t stream) {
    const float* x  = (const float*)d_in[0];
    const float* Wk = (const float*)d_in[1];
    const float* Wq = (const float*)d_in[2];
    const float* Wv = (const float*)d_in[3];

    _Float16* Qb = (_Float16*)d_ws;                        // 2 MB
    _Float16* Kb = Qb + (size_t)NB * NT * NH;              // 2 MB
    _Float16* Vt = Kb + (size_t)NB * NT * NH;              // 2 MB (transposed V)
    _Float16* Wt = Vt + (size_t)NB * NT * NH;              // 288 KB
    float* partO  = (float*)((char*)d_ws + (size_t)8  * 1024 * 1024);  // 16 MB
    float* partML = (float*)((char*)d_ws + (size_t)25 * 1024 * 1024);  // 512 KB

    wtrans_kernel<<<dim3(48, 3), dim3(256), 0, stream>>>(Wq, Wk, Wv, Wt);
    proj_kernel<<<dim3(1024), dim3(256), 0, stream>>>(x, Wt, Qb, Kb, Vt);
    attn_part_kernel<<<dim3(160, 16), dim3(64), 0, stream>>>(Qb, Kb, Vt, partO, partML);
    attn_comb_kernel<<<dim3(64, 16), dim3(64), 0, stream>>>(partO, partML, (float*)d_out);
}

// Round 7
// 67.339 us; speedup vs baseline: 1.2144x; 1.2144x over previous
//
#include <hip/hip_runtime.h>

// SelfAttentionHead: B=16, T=1024, C=768, H=64, fp32 in/out, causal softmax.
// wtrans: W -> Wt[192][768] f16.
// proj:   2-phase global_load_lds GEMM. BM=32, BN=192 (x read once), BK=32.
//         Linear LDS dest + inverse-swizzled global source (XOR chunk swizzle)
//         so ds_read_b128 fragments are ~2-way-conflict (free). 512 x 256thr.
// attn:   split-KV flash attention (<=4 KV tiles per wave), 256-thr blocks;
//         unnormalized partials (O, m, l); LSE-combine kernel merges.

typedef _Float16 half8 __attribute__((ext_vector_type(8)));
typedef _Float16 half4 __attribute__((ext_vector_type(4)));
typedef float float4v __attribute__((ext_vector_type(4)));

#define NB   16
#define NT   1024
#define NC   768
#define NH   64

typedef __attribute__((address_space(3))) unsigned int lds_u32_t;
typedef const __attribute__((address_space(1))) unsigned int g_u32_t;

__device__ __forceinline__ void gload16(const void* g, void* l) {
    __builtin_amdgcn_global_load_lds((g_u32_t*)g, (lds_u32_t*)l, 16, 0, 0);
}

// ---------------------------------------------------------------------------
// Wt[m*64+col][k] = Wm[k][col], m in {0:Q, 1:K, 2:V}. Grid (48,3) x 256.
// ---------------------------------------------------------------------------
__global__ __launch_bounds__(256) void wtrans_kernel(
    const float* __restrict__ Wq, const float* __restrict__ Wk,
    const float* __restrict__ Wv, _Float16* __restrict__ Wt)
{
    __shared__ float tile[16][68];
    const int m = blockIdx.y;
    const float* W = (m == 0) ? Wq : (m == 1) ? Wk : Wv;
    const int s = blockIdx.x;
    const int t = threadIdx.x;
    {
        const int kr = t >> 4, c4 = (t & 15) * 4;
        float4v v = *(const float4v*)(W + (size_t)(s * 16 + kr) * NH + c4);
        tile[kr][c4 + 0] = v[0]; tile[kr][c4 + 1] = v[1];
        tile[kr][c4 + 2] = v[2]; tile[kr][c4 + 3] = v[3];
    }
    __syncthreads();
    const int col = t >> 2, j = t & 3;
    half4 h;
#pragma unroll
    for (int i = 0; i < 4; ++i) h[i] = (_Float16)tile[j * 4 + i][col];
    *(half4*)(Wt + (size_t)(m * 64 + col) * NC + s * 16 + j * 4) = h;
}

// ---------------------------------------------------------------------------
// proj: grid 512 x 256 thr (4 waves). Block: 32 rows x 192 cols, BK=32.
// LDS A: f32 [32r][8 chunks of 16B], slot (r,c) holds x-chunk (c ^ (r&7)).
// LDS B: f16 [192col][4 chunks of 16B], slot (col,c) holds chunk (c ^ ((col>>1)&3)).
// Stage via global_load_lds (linear dest, pre-swizzled per-lane source).
// ---------------------------------------------------------------------------
__global__ __launch_bounds__(256) void proj_kernel(
    const float* __restrict__ x, const _Float16* __restrict__ Wt,
    _Float16* __restrict__ Qb, _Float16* __restrict__ Kb,
    _Float16* __restrict__ Vt)
{
    __shared__ float    Axl[2][32 * 32];    // 2 x 4 KB
    __shared__ _Float16 Bxl[2][192 * 32];   // 2 x 12 KB

    const int t = threadIdx.x, w = t >> 6, lane = t & 63;
    const int l15 = lane & 15, lhi = lane >> 4;
    const int m0 = blockIdx.x * 32;

    // staging source offsets (swizzled chunk within row/col)
    const int arow = w * 8 + (lane >> 3);                 // A: row this lane stages
    const int acnk = (lane & 7) ^ ((lane >> 3) & 7);      // A: source chunk
    const float* asrc = x + (size_t)(m0 + arow) * NC + acnk * 4;
    float* adst0 = &Axl[0][w * 256];                      // slot base (lane*16B implicit)

    const int bcol_i = w * 48 + (lane >> 2);              // B: col for i=0 (+16 per i)
    const int bcnk  = (lane & 3) ^ ((lane >> 3) & 3);     // B: source chunk
    const _Float16* bsrc = Wt + (size_t)bcol_i * NC + bcnk * 8;
    _Float16* bdst0 = &Bxl[0][w * 1536];

    auto STAGE = [&](int kc, int buf) {
        gload16(asrc + kc * 32, adst0 + buf * (32 * 32));
#pragma unroll
        for (int i = 0; i < 3; ++i)
            gload16(bsrc + (size_t)(i * 16) * NC + kc * 32,
                    bdst0 + buf * (192 * 32) + i * 512);
    };

    float4v acc[2][3];
#pragma unroll
    for (int i = 0; i < 2; ++i)
#pragma unroll
        for (int j = 0; j < 3; ++j)
            acc[i][j] = (float4v){0.f, 0.f, 0.f, 0.f};

    STAGE(0, 0);
    __syncthreads();

    for (int kc = 0; kc < 24; ++kc) {
        const int cur = kc & 1;
        if (kc < 23) STAGE(kc + 1, cur ^ 1);

        // A fragments: row mf*16+l15, f32 chunks lhi*2, lhi*2+1 (swizzled)
        half8 af[2];
#pragma unroll
        for (int mf = 0; mf < 2; ++mf) {
            const int r = mf * 16 + l15;
            float4v a0 = *(const float4v*)&Axl[cur][r * 32 + (((lhi * 2 + 0) ^ (l15 & 7)) * 4)];
            float4v a1 = *(const float4v*)&Axl[cur][r * 32 + (((lhi * 2 + 1) ^ (l15 & 7)) * 4)];
            half8 h;
            h[0] = (_Float16)a0[0]; h[1] = (_Float16)a0[1];
            h[2] = (_Float16)a0[2]; h[3] = (_Float16)a0[3];
            h[4] = (_Float16)a1[0]; h[5] = (_Float16)a1[1];
            h[6] = (_Float16)a1[2]; h[7] = (_Float16)a1[3];
            af[mf] = h;
        }
        // B fragments: col w*48+nf*16+l15, chunk lhi (swizzled)
        half8 bf[3];
#pragma unroll
        for (int nf = 0; nf < 3; ++nf) {
            const int col = w * 48 + nf * 16 + l15;
            bf[nf] = *(const half8*)&Bxl[cur][col * 32 + ((lhi ^ ((l15 >> 1) & 3)) * 8)];
        }
#pragma unroll
        for (int mf = 0; mf < 2; ++mf)
#pragma unroll
            for (int nf = 0; nf < 3; ++nf)
                acc[mf][nf] = __builtin_amdgcn_mfma_f32_16x16x32_f16(
                    af[mf], bf[nf], acc[mf][nf], 0, 0, 0);

        __syncthreads();
    }

#pragma unroll
    for (int nf = 0; nf < 3; ++nf) {
        const int gc  = w * 48 + nf * 16;
        const int sel = gc >> 6;
        const int col = (gc & 63) + l15;
#pragma unroll
        for (int mf = 0; mf < 2; ++mf) {
            const int row0 = m0 + mf * 16 + lhi * 4;
            if (sel == 2) {
                const int bb = row0 >> 10, tt = row0 & 1023;
                half4 h;
#pragma unroll
                for (int r = 0; r < 4; ++r) h[r] = (_Float16)acc[mf][nf][r];
                *(half4*)(Vt + ((size_t)(bb * 64 + col)) * NT + tt) = h;
            } else {
                _Float16* D = (sel == 0) ? Qb : Kb;
#pragma unroll
                for (int r = 0; r < 4; ++r)
                    D[(size_t)(row0 + r) * NH + col] = (_Float16)acc[mf][nf][r];
            }
        }
    }
}

// ---------------------------------------------------------------------------
// attn partial: grid (40, 16) x 256 thr (4 independent waves). Wave job
// i = blockIdx.x*4 + wid in 0..159 -> (qw, chunk c); chunk covers KV tiles
// [c*4, min(c*4+4, nt)), nt = qw/4+1. Unnormalized O + (m,l) partials.
// ---------------------------------------------------------------------------
__global__ __launch_bounds__(256) void attn_part_kernel(
    const _Float16* __restrict__ Qb, const _Float16* __restrict__ Kb,
    const _Float16* __restrict__ Vt, float* __restrict__ partO,
    float* __restrict__ partML)
{
    const int lane = threadIdx.x & 63, wid = threadIdx.x >> 6;
    const int l15 = lane & 15, lhi = lane >> 4;
    const int b = blockIdx.y;
    const int i = blockIdx.x * 4 + wid;
    int qw, c;
    if (i < 16)      { qw = i;                          c = 0; }
    else if (i < 48) { int j = i - 16; qw = 16 + (j >> 1); c = j & 1; }
    else if (i < 96) { int j = i - 48; int q3 = j / 3;  qw = 32 + q3; c = j - 3 * q3; }
    else             { int j = i - 96; qw = 48 + (j >> 2); c = j & 3; }

    const int q0 = qw * 16;
    const int nt = (q0 >> 6) + 1;
    const int t0 = c * 4;
    const int t1 = min(t0 + 4, nt);
    const int qrel = (q0 & 63) + l15;

    const _Float16* qsrc = Qb + ((size_t)(b * NT + q0 + l15)) * NH + lhi * 8;
    const half8 aq0 = *(const half8*)qsrc;
    const half8 aq1 = *(const half8*)(qsrc + 32);

    const _Float16* kptr = Kb + ((size_t)(b * NT + l15)) * NH + lhi * 8;
    const _Float16* vptr = Vt + ((size_t)(b * 64 + l15)) * NT + lhi * 8;

    float4v o[4];
#pragma unroll
    for (int nf = 0; nf < 4; ++nf) o[nf] = (float4v){0.f, 0.f, 0.f, 0.f};
    float m2 = -1e30f, lsum = 0.f;

    auto LOADK = [&](half8 (&bk)[8], int jt) {
#pragma unroll
        for (int kf = 0; kf < 4; ++kf)
#pragma unroll
            for (int ch = 0; ch < 2; ++ch)
                bk[kf * 2 + ch] = *(const half8*)(kptr
                    + ((size_t)(jt * 64 + kf * 16)) * NH + ch * 32);
    };

    auto STEP = [&](const half8 (&bk)[8], int jt, bool last) {
        half8 bv[8];
#pragma unroll
        for (int ks = 0; ks < 2; ++ks)
#pragma unroll
            for (int nf = 0; nf < 4; ++nf)
                bv[ks * 4 + nf] = *(const half8*)(vptr + (size_t)nf * 16 * NT
                                                  + jt * 64 + ks * 32);

        float4v sT[4];
#pragma unroll
        for (int kf = 0; kf < 4; ++kf) {
            float4v sv = (float4v){0.f, 0.f, 0.f, 0.f};
            sv = __builtin_amdgcn_mfma_f32_16x16x32_f16(bk[kf * 2 + 0], aq0, sv, 0, 0, 0);
            sv = __builtin_amdgcn_mfma_f32_16x16x32_f16(bk[kf * 2 + 1], aq1, sv, 0, 0, 0);
            sT[kf] = sv;
        }

        const float SC = 0.18033688f;   // 0.125 * log2(e)
        float p[4][4];
        float mt = -1e30f;
#pragma unroll
        for (int kf = 0; kf < 4; ++kf)
#pragma unroll
            for (int r = 0; r < 4; ++r) {
                float v = sT[kf][r] * SC;
                if (last) {
                    const int kpos = kf * 16 + lhi * 4 + r;
                    if (kpos > qrel) v = -1e30f;
                }
                p[kf][r] = v;
                mt = fmaxf(mt, v);
            }
        mt = fmaxf(mt, __shfl_xor(mt, 16));
        mt = fmaxf(mt, __shfl_xor(mt, 32));

        const float mnew = fmaxf(m2, mt);
        const float esc  = exp2f(m2 - mnew);
        float ps = 0.f;
#pragma unroll
        for (int kf = 0; kf < 4; ++kf)
#pragma unroll
            for (int r = 0; r < 4; ++r) {
                const float e = exp2f(p[kf][r] - mnew);
                p[kf][r] = e;
                ps += e;
            }
        ps += __shfl_xor(ps, 16);
        ps += __shfl_xor(ps, 32);
        lsum = lsum * esc + ps;
        m2 = mnew;

        float er[4];
#pragma unroll
        for (int r = 0; r < 4; ++r) er[r] = __shfl(esc, lhi * 4 + r);
#pragma unroll
        for (int nf = 0; nf < 4; ++nf)
#pragma unroll
            for (int r = 0; r < 4; ++r) o[nf][r] *= er[r];

        unsigned int pk[4][2];
#pragma unroll
        for (int kf = 0; kf < 4; ++kf)
#pragma unroll
            for (int pr = 0; pr < 2; ++pr) {
                auto h2 = __builtin_amdgcn_cvt_pkrtz(p[kf][2 * pr], p[kf][2 * pr + 1]);
                pk[kf][pr] = __builtin_bit_cast(unsigned int, h2);
            }

        const int sb = l15 + ((lhi & 1) * 2) * 16;
        const bool hi = (lhi >> 1) != 0;
#pragma unroll
        for (int ks = 0; ks < 2; ++ks) {
            unsigned int wv[4];
#pragma unroll
            for (int m = 0; m < 4; ++m) {
                const int L = sb + ((m >> 1) << 4);
                const unsigned int wA = (unsigned int)__shfl((int)pk[2 * ks + 0][m & 1], L);
                const unsigned int wB = (unsigned int)__shfl((int)pk[2 * ks + 1][m & 1], L);
                wv[m] = hi ? wB : wA;
            }
            union { unsigned int u[4]; half8 h; } cvt;
            cvt.u[0] = wv[0]; cvt.u[1] = wv[1]; cvt.u[2] = wv[2]; cvt.u[3] = wv[3];
            const half8 pa = cvt.h;
#pragma unroll
            for (int nf = 0; nf < 4; ++nf)
                o[nf] = __builtin_amdgcn_mfma_f32_16x16x32_f16(pa, bv[ks * 4 + nf],
                                                               o[nf], 0, 0, 0);
        }
    };

    half8 kA[8], kB[8];
    LOADK(kA, t0);
    int jt = t0;
    while (true) {
        if (jt + 1 < t1) LOADK(kB, jt + 1);
        STEP(kA, jt, jt == nt - 1);
        ++jt; if (jt == t1) break;
        if (jt + 1 < t1) LOADK(kA, jt + 1);
        STEP(kB, jt, jt == nt - 1);
        ++jt; if (jt == t1) break;
    }

    const size_t base = (size_t)((b * 64 + qw) * 4 + c);
#pragma unroll
    for (int nf = 0; nf < 4; ++nf) {
        float4v v = o[nf];
        *(float4v*)(partO + (base * 4 + nf) * 256 + lane * 4) = v;
    }
    if (lhi == 0) {
        partML[base * 32 + l15 * 2 + 0] = m2;
        partML[base * 32 + l15 * 2 + 1] = lsum;
    }
}

// ---------------------------------------------------------------------------
// combine: grid (64, 16) x 64 thr. Merge <=4 partials per q-group (LSE merge),
// normalize, write fp32 out.
// ---------------------------------------------------------------------------
__global__ __launch_bounds__(64) void attn_comb_kernel(
    const float* __restrict__ partO, const float* __restrict__ partML,
    float* __restrict__ out)
{
    const int lane = threadIdx.x;
    const int l15 = lane & 15, lhi = lane >> 4;
    const int qw = blockIdx.x, b = blockIdx.y;
    const int nch = (qw >> 4) + 1;
    const size_t gbase = (size_t)(b * 64 + qw) * 4;

    float mc[4][4], lc[4][4];
    float M[4];
#pragma unroll
    for (int r = 0; r < 4; ++r) M[r] = -1e30f;
#pragma unroll
    for (int cc = 0; cc < 4; ++cc) {
        if (cc < nch) {
#pragma unroll
            for (int r = 0; r < 4; ++r) {
                const int row = lhi * 4 + r;
                mc[cc][r] = partML[(gbase + cc) * 32 + row * 2 + 0];
                lc[cc][r] = partML[(gbase + cc) * 32 + row * 2 + 1];
                M[r] = fmaxf(M[r], mc[cc][r]);
            }
        }
    }
    float sc[4][4], L[4];
#pragma unroll
    for (int r = 0; r < 4; ++r) L[r] = 0.f;
#pragma unroll
    for (int cc = 0; cc < 4; ++cc) {
        if (cc < nch) {
#pragma unroll
            for (int r = 0; r < 4; ++r) {
                sc[cc][r] = exp2f(mc[cc][r] - M[r]);
                L[r] += lc[cc][r] * sc[cc][r];
            }
        }
    }
    float linv[4];
#pragma unroll
    for (int r = 0; r < 4; ++r) linv[r] = 1.f / L[r];

#pragma unroll
    for (int nf = 0; nf < 4; ++nf) {
        float acc[4] = {0.f, 0.f, 0.f, 0.f};
#pragma unroll
        for (int cc = 0; cc < 4; ++cc) {
            if (cc < nch) {
                float4v v = *(const float4v*)(partO + (gbase + cc) * 1024
                                              + nf * 256 + lane * 4);
#pragma unroll
                for (int r = 0; r < 4; ++r) acc[r] += v[r] * sc[cc][r];
            }
        }
#pragma unroll
        for (int r = 0; r < 4; ++r) {
            const int row = qw * 16 + lhi * 4 + r;
            out[((size_t)(b * NT + row)) * NH + nf * 16 + l15] = acc[r] * linv[r];
        }
    }
}

extern "C" void kernel_launch(void* const* d_in, const int* in_sizes, int n_in,
                              void* d_out, int out_size, void* d_ws, size_t ws_size,
                              hipStream_t stream) {
    const float* x  = (const float*)d_in[0];
    const float* Wk = (const float*)d_in[1];
    const float* Wq = (const float*)d_in[2];
    const float* Wv = (const float*)d_in[3];

    _Float16* Qb = (_Float16*)d_ws;                        // 2 MB
    _Float16* Kb = Qb + (size_t)NB * NT * NH;              // 2 MB
    _Float16* Vt = Kb + (size_t)NB * NT * NH;              // 2 MB (transposed V)
    _Float16* Wt = Vt + (size_t)NB * NT * NH;              // 288 KB
    float* partO  = (float*)((char*)d_ws + (size_t)8  * 1024 * 1024);  // 16 MB
    float* partML = (float*)((char*)d_ws + (size_t)25 * 1024 * 1024);  // 512 KB

    wtrans_kernel<<<dim3(48, 3), dim3(256), 0, stream>>>(Wq, Wk, Wv, Wt);
    proj_kernel<<<dim3(512), dim3(256), 0, stream>>>(x, Wt, Qb, Kb, Vt);
    attn_part_kernel<<<dim3(40, 16), dim3(256), 0, stream>>>(Qb, Kb, Vt, partO, partML);
    attn_comb_kernel<<<dim3(64, 16), dim3(64), 0, stream>>>(partO, partML, (float*)d_out);
}

// Round 8
// 65.402 us; speedup vs baseline: 1.2503x; 1.0296x over previous
//
#include <hip/hip_runtime.h>

// SelfAttentionHead: B=16, T=1024, C=768, H=64, fp32 in/out, causal softmax.
// wtrans: W -> Wt[192][768] f16.
// proj:   3-buffer global_load_lds GEMM with COUNTED vmcnt (T3/T4): raw
//         s_barrier + s_waitcnt vmcnt(4); prefetch depth 2 K-steps; loads
//         never drain to 0 inside the loop. BM=32, BN=192, BK=32, 512x256.
// attn:   split-KV flash attention (<=4 KV tiles per wave), 256-thr blocks;
//         unnormalized partials (O, m, l); LSE-combine kernel merges.

typedef _Float16 half8 __attribute__((ext_vector_type(8)));
typedef _Float16 half4 __attribute__((ext_vector_type(4)));
typedef float float4v __attribute__((ext_vector_type(4)));

#define NB   16
#define NT   1024
#define NC   768
#define NH   64

typedef __attribute__((address_space(3))) unsigned int lds_u32_t;
typedef const __attribute__((address_space(1))) unsigned int g_u32_t;

__device__ __forceinline__ void gload16(const void* g, void* l) {
    __builtin_amdgcn_global_load_lds((g_u32_t*)g, (lds_u32_t*)l, 16, 0, 0);
}

// ---------------------------------------------------------------------------
// Wt[m*64+col][k] = Wm[k][col], m in {0:Q, 1:K, 2:V}. Grid (48,3) x 256.
// ---------------------------------------------------------------------------
__global__ __launch_bounds__(256) void wtrans_kernel(
    const float* __restrict__ Wq, const float* __restrict__ Wk,
    const float* __restrict__ Wv, _Float16* __restrict__ Wt)
{
    __shared__ float tile[16][68];
    const int m = blockIdx.y;
    const float* W = (m == 0) ? Wq : (m == 1) ? Wk : Wv;
    const int s = blockIdx.x;
    const int t = threadIdx.x;
    {
        const int kr = t >> 4, c4 = (t & 15) * 4;
        float4v v = *(const float4v*)(W + (size_t)(s * 16 + kr) * NH + c4);
        tile[kr][c4 + 0] = v[0]; tile[kr][c4 + 1] = v[1];
        tile[kr][c4 + 2] = v[2]; tile[kr][c4 + 3] = v[3];
    }
    __syncthreads();
    const int col = t >> 2, j = t & 3;
    half4 h;
#pragma unroll
    for (int i = 0; i < 4; ++i) h[i] = (_Float16)tile[j * 4 + i][col];
    *(half4*)(Wt + (size_t)(m * 64 + col) * NC + s * 16 + j * 4) = h;
}

// ---------------------------------------------------------------------------
// proj: grid 512 x 256 thr (4 waves). Block: 32 rows x 192 cols, BK=32.
// 3 LDS buffers; counted-vmcnt pipeline (prefetch depth 2).
// LDS A: f32 [32r][8 chunks of 16B], slot (r,c) holds x-chunk (c ^ (r&7)).
// LDS B: f16 [192col][4 chunks of 16B], slot (col,c) holds chunk (c ^ ((col>>1)&3)).
// ---------------------------------------------------------------------------
__global__ __launch_bounds__(256) void proj_kernel(
    const float* __restrict__ x, const _Float16* __restrict__ Wt,
    _Float16* __restrict__ Qb, _Float16* __restrict__ Kb,
    _Float16* __restrict__ Vt)
{
    __shared__ float    Axl[3][32 * 32];    // 3 x 4 KB
    __shared__ _Float16 Bxl[3][192 * 32];   // 3 x 12 KB

    const int t = threadIdx.x, w = t >> 6, lane = t & 63;
    const int l15 = lane & 15, lhi = lane >> 4;
    const int m0 = blockIdx.x * 32;

    // staging source offsets (swizzled chunk within row/col)
    const int arow = w * 8 + (lane >> 3);                 // A: row this lane stages
    const int acnk = (lane & 7) ^ ((lane >> 3) & 7);      // A: source chunk
    const float* asrc = x + (size_t)(m0 + arow) * NC + acnk * 4;
    float* adst0 = &Axl[0][w * 256];                      // lane*16B implicit

    const int bcnk  = (lane & 3) ^ ((lane >> 3) & 3);     // B: source chunk
    const _Float16* bsrc = Wt + (size_t)(w * 48 + (lane >> 2)) * NC + bcnk * 8;
    _Float16* bdst0 = &Bxl[0][w * 1536];

    auto STAGE = [&](int kc, int buf) {
        gload16(asrc + kc * 32, adst0 + buf * (32 * 32));
#pragma unroll
        for (int i = 0; i < 3; ++i)
            gload16(bsrc + (size_t)(i * 16) * NC + kc * 32,
                    bdst0 + buf * (192 * 32) + i * 512);
    };

    float4v acc[2][3];
#pragma unroll
    for (int i = 0; i < 2; ++i)
#pragma unroll
        for (int j = 0; j < 3; ++j)
            acc[i][j] = (float4v){0.f, 0.f, 0.f, 0.f};

    STAGE(0, 0);
    STAGE(1, 1);

    int cur = 0;
    for (int kc = 0; kc < 24; ++kc) {
        // own stage(kc) complete (stage(kc+1)'s 4 loads may stay in flight)
        if (kc < 22) asm volatile("s_waitcnt vmcnt(4)" ::: "memory");
        else         asm volatile("s_waitcnt vmcnt(0)" ::: "memory");
        __builtin_amdgcn_s_barrier();   // all waves' stage(kc) complete
        asm volatile("" ::: "memory");

        // prefetch kc+2 into the buffer read at iter kc-1 (safe past barrier)
        if (kc + 2 < 24) {
            const int st = (cur >= 1) ? cur - 1 : 2;   // (cur+2)%3
            STAGE(kc + 2, st);
        }

        // A fragments: row mf*16+l15, f32 chunks lhi*2, lhi*2+1 (swizzled)
        half8 af[2];
#pragma unroll
        for (int mf = 0; mf < 2; ++mf) {
            const int r = mf * 16 + l15;
            float4v a0 = *(const float4v*)&Axl[cur][r * 32 + (((lhi * 2 + 0) ^ (l15 & 7)) * 4)];
            float4v a1 = *(const float4v*)&Axl[cur][r * 32 + (((lhi * 2 + 1) ^ (l15 & 7)) * 4)];
            half8 h;
            h[0] = (_Float16)a0[0]; h[1] = (_Float16)a0[1];
            h[2] = (_Float16)a0[2]; h[3] = (_Float16)a0[3];
            h[4] = (_Float16)a1[0]; h[5] = (_Float16)a1[1];
            h[6] = (_Float16)a1[2]; h[7] = (_Float16)a1[3];
            af[mf] = h;
        }
        // B fragments: col w*48+nf*16+l15, chunk lhi (swizzled)
        half8 bf[3];
#pragma unroll
        for (int nf = 0; nf < 3; ++nf) {
            const int col = w * 48 + nf * 16 + l15;
            bf[nf] = *(const half8*)&Bxl[cur][col * 32 + ((lhi ^ ((l15 >> 1) & 3)) * 8)];
        }
#pragma unroll
        for (int mf = 0; mf < 2; ++mf)
#pragma unroll
            for (int nf = 0; nf < 3; ++nf)
                acc[mf][nf] = __builtin_amdgcn_mfma_f32_16x16x32_f16(
                    af[mf], bf[nf], acc[mf][nf], 0, 0, 0);

        cur = (cur == 2) ? 0 : cur + 1;
    }

#pragma unroll
    for (int nf = 0; nf < 3; ++nf) {
        const int gc  = w * 48 + nf * 16;
        const int sel = gc >> 6;
        const int col = (gc & 63) + l15;
#pragma unroll
        for (int mf = 0; mf < 2; ++mf) {
            const int row0 = m0 + mf * 16 + lhi * 4;
            if (sel == 2) {
                const int bb = row0 >> 10, tt = row0 & 1023;
                half4 h;
#pragma unroll
                for (int r = 0; r < 4; ++r) h[r] = (_Float16)acc[mf][nf][r];
                *(half4*)(Vt + ((size_t)(bb * 64 + col)) * NT + tt) = h;
            } else {
                _Float16* D = (sel == 0) ? Qb : Kb;
#pragma unroll
                for (int r = 0; r < 4; ++r)
                    D[(size_t)(row0 + r) * NH + col] = (_Float16)acc[mf][nf][r];
            }
        }
    }
}

// ---------------------------------------------------------------------------
// attn partial: grid (40, 16) x 256 thr (4 independent waves). Wave job
// i = blockIdx.x*4 + wid in 0..159 -> (qw, chunk c); chunk covers KV tiles
// [c*4, min(c*4+4, nt)), nt = qw/4+1. Unnormalized O + (m,l) partials.
// ---------------------------------------------------------------------------
__global__ __launch_bounds__(256) void attn_part_kernel(
    const _Float16* __restrict__ Qb, const _Float16* __restrict__ Kb,
    const _Float16* __restrict__ Vt, float* __restrict__ partO,
    float* __restrict__ partML)
{
    const int lane = threadIdx.x & 63, wid = threadIdx.x >> 6;
    const int l15 = lane & 15, lhi = lane >> 4;
    const int b = blockIdx.y;
    const int i = blockIdx.x * 4 + wid;
    int qw, c;
    if (i < 16)      { qw = i;                          c = 0; }
    else if (i < 48) { int j = i - 16; qw = 16 + (j >> 1); c = j & 1; }
    else if (i < 96) { int j = i - 48; int q3 = j / 3;  qw = 32 + q3; c = j - 3 * q3; }
    else             { int j = i - 96; qw = 48 + (j >> 2); c = j & 3; }

    const int q0 = qw * 16;
    const int nt = (q0 >> 6) + 1;
    const int t0 = c * 4;
    const int t1 = min(t0 + 4, nt);
    const int qrel = (q0 & 63) + l15;

    const _Float16* qsrc = Qb + ((size_t)(b * NT + q0 + l15)) * NH + lhi * 8;
    const half8 aq0 = *(const half8*)qsrc;
    const half8 aq1 = *(const half8*)(qsrc + 32);

    const _Float16* kptr = Kb + ((size_t)(b * NT + l15)) * NH + lhi * 8;
    const _Float16* vptr = Vt + ((size_t)(b * 64 + l15)) * NT + lhi * 8;

    float4v o[4];
#pragma unroll
    for (int nf = 0; nf < 4; ++nf) o[nf] = (float4v){0.f, 0.f, 0.f, 0.f};
    float m2 = -1e30f, lsum = 0.f;

    auto LOADK = [&](half8 (&bk)[8], int jt) {
#pragma unroll
        for (int kf = 0; kf < 4; ++kf)
#pragma unroll
            for (int ch = 0; ch < 2; ++ch)
                bk[kf * 2 + ch] = *(const half8*)(kptr
                    + ((size_t)(jt * 64 + kf * 16)) * NH + ch * 32);
    };

    auto STEP = [&](const half8 (&bk)[8], int jt, bool last) {
        half8 bv[8];
#pragma unroll
        for (int ks = 0; ks < 2; ++ks)
#pragma unroll
            for (int nf = 0; nf < 4; ++nf)
                bv[ks * 4 + nf] = *(const half8*)(vptr + (size_t)nf * 16 * NT
                                                  + jt * 64 + ks * 32);

        float4v sT[4];
#pragma unroll
        for (int kf = 0; kf < 4; ++kf) {
            float4v sv = (float4v){0.f, 0.f, 0.f, 0.f};
            sv = __builtin_amdgcn_mfma_f32_16x16x32_f16(bk[kf * 2 + 0], aq0, sv, 0, 0, 0);
            sv = __builtin_amdgcn_mfma_f32_16x16x32_f16(bk[kf * 2 + 1], aq1, sv, 0, 0, 0);
            sT[kf] = sv;
        }

        const float SC = 0.18033688f;   // 0.125 * log2(e)
        float p[4][4];
        float mt = -1e30f;
#pragma unroll
        for (int kf = 0; kf < 4; ++kf)
#pragma unroll
            for (int r = 0; r < 4; ++r) {
                float v = sT[kf][r] * SC;
                if (last) {
                    const int kpos = kf * 16 + lhi * 4 + r;
                    if (kpos > qrel) v = -1e30f;
                }
                p[kf][r] = v;
                mt = fmaxf(mt, v);
            }
        mt = fmaxf(mt, __shfl_xor(mt, 16));
        mt = fmaxf(mt, __shfl_xor(mt, 32));

        const float mnew = fmaxf(m2, mt);
        const float esc  = exp2f(m2 - mnew);
        float ps = 0.f;
#pragma unroll
        for (int kf = 0; kf < 4; ++kf)
#pragma unroll
            for (int r = 0; r < 4; ++r) {
                const float e = exp2f(p[kf][r] - mnew);
                p[kf][r] = e;
                ps += e;
            }
        ps += __shfl_xor(ps, 16);
        ps += __shfl_xor(ps, 32);
        lsum = lsum * esc + ps;
        m2 = mnew;

        float er[4];
#pragma unroll
        for (int r = 0; r < 4; ++r) er[r] = __shfl(esc, lhi * 4 + r);
#pragma unroll
        for (int nf = 0; nf < 4; ++nf)
#pragma unroll
            for (int r = 0; r < 4; ++r) o[nf][r] *= er[r];

        unsigned int pk[4][2];
#pragma unroll
        for (int kf = 0; kf < 4; ++kf)
#pragma unroll
            for (int pr = 0; pr < 2; ++pr) {
                auto h2 = __builtin_amdgcn_cvt_pkrtz(p[kf][2 * pr], p[kf][2 * pr + 1]);
                pk[kf][pr] = __builtin_bit_cast(unsigned int, h2);
            }

        const int sb = l15 + ((lhi & 1) * 2) * 16;
        const bool hi = (lhi >> 1) != 0;
#pragma unroll
        for (int ks = 0; ks < 2; ++ks) {
            unsigned int wv[4];
#pragma unroll
            for (int m = 0; m < 4; ++m) {
                const int L = sb + ((m >> 1) << 4);
                const unsigned int wA = (unsigned int)__shfl((int)pk[2 * ks + 0][m & 1], L);
                const unsigned int wB = (unsigned int)__shfl((int)pk[2 * ks + 1][m & 1], L);
                wv[m] = hi ? wB : wA;
            }
            union { unsigned int u[4]; half8 h; } cvt;
            cvt.u[0] = wv[0]; cvt.u[1] = wv[1]; cvt.u[2] = wv[2]; cvt.u[3] = wv[3];
            const half8 pa = cvt.h;
#pragma unroll
            for (int nf = 0; nf < 4; ++nf)
                o[nf] = __builtin_amdgcn_mfma_f32_16x16x32_f16(pa, bv[ks * 4 + nf],
                                                               o[nf], 0, 0, 0);
        }
    };

    half8 kA[8], kB[8];
    LOADK(kA, t0);
    int jt = t0;
    while (true) {
        if (jt + 1 < t1) LOADK(kB, jt + 1);
        STEP(kA, jt, jt == nt - 1);
        ++jt; if (jt == t1) break;
        if (jt + 1 < t1) LOADK(kA, jt + 1);
        STEP(kB, jt, jt == nt - 1);
        ++jt; if (jt == t1) break;
    }

    const size_t base = (size_t)((b * 64 + qw) * 4 + c);
#pragma unroll
    for (int nf = 0; nf < 4; ++nf) {
        float4v v = o[nf];
        *(float4v*)(partO + (base * 4 + nf) * 256 + lane * 4) = v;
    }
    if (lhi == 0) {
        partML[base * 32 + l15 * 2 + 0] = m2;
        partML[base * 32 + l15 * 2 + 1] = lsum;
    }
}

// ---------------------------------------------------------------------------
// combine: grid (64, 16) x 64 thr. Merge <=4 partials per q-group (LSE merge),
// normalize, write fp32 out.
// ---------------------------------------------------------------------------
__global__ __launch_bounds__(64) void attn_comb_kernel(
    const float* __restrict__ partO, const float* __restrict__ partML,
    float* __restrict__ out)
{
    const int lane = threadIdx.x;
    const int l15 = lane & 15, lhi = lane >> 4;
    const int qw = blockIdx.x, b = blockIdx.y;
    const int nch = (qw >> 4) + 1;
    const size_t gbase = (size_t)(b * 64 + qw) * 4;

    float mc[4][4], lc[4][4];
    float M[4];
#pragma unroll
    for (int r = 0; r < 4; ++r) M[r] = -1e30f;
#pragma unroll
    for (int cc = 0; cc < 4; ++cc) {
        if (cc < nch) {
#pragma unroll
            for (int r = 0; r < 4; ++r) {
                const int row = lhi * 4 + r;
                mc[cc][r] = partML[(gbase + cc) * 32 + row * 2 + 0];
                lc[cc][r] = partML[(gbase + cc) * 32 + row * 2 + 1];
                M[r] = fmaxf(M[r], mc[cc][r]);
            }
        }
    }
    float sc[4][4], L[4];
#pragma unroll
    for (int r = 0; r < 4; ++r) L[r] = 0.f;
#pragma unroll
    for (int cc = 0; cc < 4; ++cc) {
        if (cc < nch) {
#pragma unroll
            for (int r = 0; r < 4; ++r) {
                sc[cc][r] = exp2f(mc[cc][r] - M[r]);
                L[r] += lc[cc][r] * sc[cc][r];
            }
        }
    }
    float linv[4];
#pragma unroll
    for (int r = 0; r < 4; ++r) linv[r] = 1.f / L[r];

#pragma unroll
    for (int nf = 0; nf < 4; ++nf) {
        float acc[4] = {0.f, 0.f, 0.f, 0.f};
#pragma unroll
        for (int cc = 0; cc < 4; ++cc) {
            if (cc < nch) {
                float4v v = *(const float4v*)(partO + (gbase + cc) * 1024
                                              + nf * 256 + lane * 4);
#pragma unroll
                for (int r = 0; r < 4; ++r) acc[r] += v[r] * sc[cc][r];
            }
        }
#pragma unroll
        for (int r = 0; r < 4; ++r) {
            const int row = qw * 16 + lhi * 4 + r;
            out[((size_t)(b * NT + row)) * NH + nf * 16 + l15] = acc[r] * linv[r];
        }
    }
}

extern "C" void kernel_launch(void* const* d_in, const int* in_sizes, int n_in,
                              void* d_out, int out_size, void* d_ws, size_t ws_size,
                              hipStream_t stream) {
    const float* x  = (const float*)d_in[0];
    const float* Wk = (const float*)d_in[1];
    const float* Wq = (const float*)d_in[2];
    const float* Wv = (const float*)d_in[3];

    _Float16* Qb = (_Float16*)d_ws;                        // 2 MB
    _Float16* Kb = Qb + (size_t)NB * NT * NH;              // 2 MB
    _Float16* Vt = Kb + (size_t)NB * NT * NH;              // 2 MB (transposed V)
    _Float16* Wt = Vt + (size_t)NB * NT * NH;              // 288 KB
    float* partO  = (float*)((char*)d_ws + (size_t)8  * 1024 * 1024);  // 16 MB
    float* partML = (float*)((char*)d_ws + (size_t)25 * 1024 * 1024);  // 512 KB

    wtrans_kernel<<<dim3(48, 3), dim3(256), 0, stream>>>(Wq, Wk, Wv, Wt);
    proj_kernel<<<dim3(512), dim3(256), 0, stream>>>(x, Wt, Qb, Kb, Vt);
    attn_part_kernel<<<dim3(40, 16), dim3(256), 0, stream>>>(Qb, Kb, Vt, partO, partML);
    attn_comb_kernel<<<dim3(64, 16), dim3(64), 0, stream>>>(partO, partML, (float*)d_out);
}

// Round 9
// 62.114 us; speedup vs baseline: 1.3165x; 1.0529x over previous
//
#include <hip/hip_runtime.h>

// SelfAttentionHead: B=16, T=1024, C=768, H=64, fp32 in/out, causal softmax.
// wtrans: W -> Wt[192][768] f16.
// proj:   R3 register-staged LDS GEMM (BM=32, BK=64, 512x256) with prefetch
//         DEPTH 2: tiles kc+1 and kc+2 in flight -> ~1.4k cy load window.
// attn:   split-KV flash attention; single kA K-buffer (prefetch-in-place),
//         launch_bounds(256,3) to cap VGPR; partials + LSE-combine.

typedef _Float16 half8 __attribute__((ext_vector_type(8)));
typedef _Float16 half4 __attribute__((ext_vector_type(4)));
typedef float float4v __attribute__((ext_vector_type(4)));

#define NB   16
#define NT   1024
#define NC   768
#define NH   64

// ---------------------------------------------------------------------------
// Wt[m*64+col][k] = Wm[k][col], m in {0:Q, 1:K, 2:V}. Grid (48,3) x 256.
// ---------------------------------------------------------------------------
__global__ __launch_bounds__(256) void wtrans_kernel(
    const float* __restrict__ Wq, const float* __restrict__ Wk,
    const float* __restrict__ Wv, _Float16* __restrict__ Wt)
{
    __shared__ float tile[16][68];
    const int m = blockIdx.y;
    const float* W = (m == 0) ? Wq : (m == 1) ? Wk : Wv;
    const int s = blockIdx.x;
    const int t = threadIdx.x;
    {
        const int kr = t >> 4, c4 = (t & 15) * 4;
        float4v v = *(const float4v*)(W + (size_t)(s * 16 + kr) * NH + c4);
        tile[kr][c4 + 0] = v[0]; tile[kr][c4 + 1] = v[1];
        tile[kr][c4 + 2] = v[2]; tile[kr][c4 + 3] = v[3];
    }
    __syncthreads();
    const int col = t >> 2, j = t & 3;
    half4 h;
#pragma unroll
    for (int i = 0; i < 4; ++i) h[i] = (_Float16)tile[j * 4 + i][col];
    *(half4*)(Wt + (size_t)(m * 64 + col) * NC + s * 16 + j * 4) = h;
}

// ---------------------------------------------------------------------------
// proj: grid 512 x 256 thr (4 waves). Block: 32 rows x 192 cols, BK=64.
// Register prefetch depth 2 (tiles kc+1, kc+2 in flight across 2 barriers).
// ---------------------------------------------------------------------------
__global__ __launch_bounds__(256) void proj_kernel(
    const float* __restrict__ x, const _Float16* __restrict__ Wt,
    _Float16* __restrict__ Qb, _Float16* __restrict__ Kb,
    _Float16* __restrict__ Vt)
{
    __shared__ _Float16 xl[32][68];

    const int t   = threadIdx.x;
    const int wid = t >> 6, lane = t & 63;
    const int l15 = lane & 15, lhi = lane >> 4;
    const int m0  = blockIdx.x * 32;
    const int srow = t >> 3, sc0 = (t & 7) * 8;

    const float*    xsrc  = x  + (size_t)(m0 + srow) * NC + sc0;
    const _Float16* wbase = Wt + (size_t)(wid * 48 + l15) * NC + lhi * 8;

    float4v acc[2][3];
#pragma unroll
    for (int i = 0; i < 2; ++i)
#pragma unroll
        for (int j = 0; j < 3; ++j)
            acc[i][j] = (float4v){0.f, 0.f, 0.f, 0.f};

    // depth-2 register pipeline: slots hold tiles kc, kc+1
    float4v g0[2], g1[2];
    half8 bf[2][3][2];
#pragma unroll
    for (int p = 0; p < 2; ++p) {
        g0[p] = *(const float4v*)(xsrc + p * 64);
        g1[p] = *(const float4v*)(xsrc + p * 64 + 4);
#pragma unroll
        for (int nf = 0; nf < 3; ++nf)
#pragma unroll
            for (int ks = 0; ks < 2; ++ks)
                bf[p][nf][ks] = *(const half8*)(wbase + (size_t)nf * 16 * NC
                                                + p * 64 + ks * 32);
    }

#pragma unroll 2
    for (int kc = 0; kc < 12; ++kc) {
        const int cur = kc & 1;
        __syncthreads();   // previous iteration's LDS reads done
        {
            half8 h;
            h[0] = (_Float16)g0[cur][0]; h[1] = (_Float16)g0[cur][1];
            h[2] = (_Float16)g0[cur][2]; h[3] = (_Float16)g0[cur][3];
            h[4] = (_Float16)g1[cur][0]; h[5] = (_Float16)g1[cur][1];
            h[6] = (_Float16)g1[cur][2]; h[7] = (_Float16)g1[cur][3];
            *(half8*)&xl[srow][sc0] = h;
        }
        __syncthreads();

        half8 bcur[3][2];
#pragma unroll
        for (int nf = 0; nf < 3; ++nf)
#pragma unroll
            for (int ks = 0; ks < 2; ++ks) bcur[nf][ks] = bf[cur][nf][ks];

        if (kc + 2 < 12) {   // refill slot with tile kc+2 (consumed 2 steps later)
            g0[cur] = *(const float4v*)(xsrc + (kc + 2) * 64);
            g1[cur] = *(const float4v*)(xsrc + (kc + 2) * 64 + 4);
#pragma unroll
            for (int nf = 0; nf < 3; ++nf)
#pragma unroll
                for (int ks = 0; ks < 2; ++ks)
                    bf[cur][nf][ks] = *(const half8*)(wbase + (size_t)nf * 16 * NC
                                                      + (kc + 2) * 64 + ks * 32);
        }

        half8 af[2][2];
#pragma unroll
        for (int mf = 0; mf < 2; ++mf)
#pragma unroll
            for (int ks = 0; ks < 2; ++ks)
                af[mf][ks] = *(const half8*)&xl[mf * 16 + l15][ks * 32 + lhi * 8];

#pragma unroll
        for (int ks = 0; ks < 2; ++ks)
#pragma unroll
            for (int mf = 0; mf < 2; ++mf)
#pragma unroll
                for (int nf = 0; nf < 3; ++nf)
                    acc[mf][nf] = __builtin_amdgcn_mfma_f32_16x16x32_f16(
                        af[mf][ks], bcur[nf][ks], acc[mf][nf], 0, 0, 0);
    }

#pragma unroll
    for (int nf = 0; nf < 3; ++nf) {
        const int gc  = wid * 48 + nf * 16;
        const int sel = gc >> 6;
        const int col = (gc & 63) + l15;
#pragma unroll
        for (int mf = 0; mf < 2; ++mf) {
            const int row0 = m0 + mf * 16 + lhi * 4;
            if (sel == 2) {
                const int bb = row0 >> 10, tt = row0 & 1023;
                half4 h;
#pragma unroll
                for (int r = 0; r < 4; ++r) h[r] = (_Float16)acc[mf][nf][r];
                *(half4*)(Vt + ((size_t)(bb * 64 + col)) * NT + tt) = h;
            } else {
                _Float16* D = (sel == 0) ? Qb : Kb;
#pragma unroll
                for (int r = 0; r < 4; ++r)
                    D[(size_t)(row0 + r) * NH + col] = (_Float16)acc[mf][nf][r];
            }
        }
    }
}

// ---------------------------------------------------------------------------
// attn partial: grid (40, 16) x 256 thr (4 independent waves), LB(256,3).
// Wave job i -> (qw, chunk c); chunk = KV tiles [c*4, min(c*4+4, nt)).
// Single K buffer: K(jt+1) prefetched into kA right after QK consumes it.
// ---------------------------------------------------------------------------
__global__ __launch_bounds__(256, 3) void attn_part_kernel(
    const _Float16* __restrict__ Qb, const _Float16* __restrict__ Kb,
    const _Float16* __restrict__ Vt, float* __restrict__ partO,
    float* __restrict__ partML)
{
    const int lane = threadIdx.x & 63, wid = threadIdx.x >> 6;
    const int l15 = lane & 15, lhi = lane >> 4;
    const int b = blockIdx.y;
    const int i = blockIdx.x * 4 + wid;
    int qw, c;
    if (i < 16)      { qw = i;                          c = 0; }
    else if (i < 48) { int j = i - 16; qw = 16 + (j >> 1); c = j & 1; }
    else if (i < 96) { int j = i - 48; int q3 = j / 3;  qw = 32 + q3; c = j - 3 * q3; }
    else             { int j = i - 96; qw = 48 + (j >> 2); c = j & 3; }

    const int q0 = qw * 16;
    const int nt = (q0 >> 6) + 1;
    const int t0 = c * 4;
    const int t1 = min(t0 + 4, nt);
    const int qrel = (q0 & 63) + l15;

    const _Float16* qsrc = Qb + ((size_t)(b * NT + q0 + l15)) * NH + lhi * 8;
    const half8 aq0 = *(const half8*)qsrc;
    const half8 aq1 = *(const half8*)(qsrc + 32);

    const _Float16* kptr = Kb + ((size_t)(b * NT + l15)) * NH + lhi * 8;
    const _Float16* vptr = Vt + ((size_t)(b * 64 + l15)) * NT + lhi * 8;

    float4v o[4];
#pragma unroll
    for (int nf = 0; nf < 4; ++nf) o[nf] = (float4v){0.f, 0.f, 0.f, 0.f};
    float m2 = -1e30f, lsum = 0.f;

    half8 kA[8];
#pragma unroll
    for (int kf = 0; kf < 4; ++kf)
#pragma unroll
        for (int ch = 0; ch < 2; ++ch)
            kA[kf * 2 + ch] = *(const half8*)(kptr
                + ((size_t)(t0 * 64 + kf * 16)) * NH + ch * 32);

    for (int jt = t0; jt < t1; ++jt) {
        const bool last = (jt == nt - 1);

        // V fragments for this tile (consumed after softmax)
        half8 bv[8];
#pragma unroll
        for (int ks = 0; ks < 2; ++ks)
#pragma unroll
            for (int nf = 0; nf < 4; ++nf)
                bv[ks * 4 + nf] = *(const half8*)(vptr + (size_t)nf * 16 * NT
                                                  + jt * 64 + ks * 32);

        // S^T = K * Q^T
        float4v sT[4];
#pragma unroll
        for (int kf = 0; kf < 4; ++kf) {
            float4v sv = (float4v){0.f, 0.f, 0.f, 0.f};
            sv = __builtin_amdgcn_mfma_f32_16x16x32_f16(kA[kf * 2 + 0], aq0, sv, 0, 0, 0);
            sv = __builtin_amdgcn_mfma_f32_16x16x32_f16(kA[kf * 2 + 1], aq1, sv, 0, 0, 0);
            sT[kf] = sv;
        }

        // prefetch next K tile into the same buffer (QK already consumed kA)
        if (jt + 1 < t1) {
#pragma unroll
            for (int kf = 0; kf < 4; ++kf)
#pragma unroll
                for (int ch = 0; ch < 2; ++ch)
                    kA[kf * 2 + ch] = *(const half8*)(kptr
                        + ((size_t)((jt + 1) * 64 + kf * 16)) * NH + ch * 32);
        }

        const float SC = 0.18033688f;   // 0.125 * log2(e)
        float p[4][4];
        float mt = -1e30f;
#pragma unroll
        for (int kf = 0; kf < 4; ++kf)
#pragma unroll
            for (int r = 0; r < 4; ++r) {
                float v = sT[kf][r] * SC;
                if (last) {
                    const int kpos = kf * 16 + lhi * 4 + r;
                    if (kpos > qrel) v = -1e30f;
                }
                p[kf][r] = v;
                mt = fmaxf(mt, v);
            }
        mt = fmaxf(mt, __shfl_xor(mt, 16));
        mt = fmaxf(mt, __shfl_xor(mt, 32));

        const float mnew = fmaxf(m2, mt);
        const float esc  = exp2f(m2 - mnew);
        float ps = 0.f;
#pragma unroll
        for (int kf = 0; kf < 4; ++kf)
#pragma unroll
            for (int r = 0; r < 4; ++r) {
                const float e = exp2f(p[kf][r] - mnew);
                p[kf][r] = e;
                ps += e;
            }
        ps += __shfl_xor(ps, 16);
        ps += __shfl_xor(ps, 32);
        lsum = lsum * esc + ps;
        m2 = mnew;

        float er[4];
#pragma unroll
        for (int r = 0; r < 4; ++r) er[r] = __shfl(esc, lhi * 4 + r);
#pragma unroll
        for (int nf = 0; nf < 4; ++nf)
#pragma unroll
            for (int r = 0; r < 4; ++r) o[nf][r] *= er[r];

        unsigned int pk[4][2];
#pragma unroll
        for (int kf = 0; kf < 4; ++kf)
#pragma unroll
            for (int pr = 0; pr < 2; ++pr) {
                auto h2 = __builtin_amdgcn_cvt_pkrtz(p[kf][2 * pr], p[kf][2 * pr + 1]);
                pk[kf][pr] = __builtin_bit_cast(unsigned int, h2);
            }

        const int sb = l15 + ((lhi & 1) * 2) * 16;
        const bool hi = (lhi >> 1) != 0;
#pragma unroll
        for (int ks = 0; ks < 2; ++ks) {
            unsigned int wv[4];
#pragma unroll
            for (int m = 0; m < 4; ++m) {
                const int L = sb + ((m >> 1) << 4);
                const unsigned int wA = (unsigned int)__shfl((int)pk[2 * ks + 0][m & 1], L);
                const unsigned int wB = (unsigned int)__shfl((int)pk[2 * ks + 1][m & 1], L);
                wv[m] = hi ? wB : wA;
            }
            union { unsigned int u[4]; half8 h; } cvt;
            cvt.u[0] = wv[0]; cvt.u[1] = wv[1]; cvt.u[2] = wv[2]; cvt.u[3] = wv[3];
            const half8 pa = cvt.h;
#pragma unroll
            for (int nf = 0; nf < 4; ++nf)
                o[nf] = __builtin_amdgcn_mfma_f32_16x16x32_f16(pa, bv[ks * 4 + nf],
                                                               o[nf], 0, 0, 0);
        }
    }

    const size_t base = (size_t)((b * 64 + qw) * 4 + c);
#pragma unroll
    for (int nf = 0; nf < 4; ++nf) {
        float4v v = o[nf];
        *(float4v*)(partO + (base * 4 + nf) * 256 + lane * 4) = v;
    }
    if (lhi == 0) {
        partML[base * 32 + l15 * 2 + 0] = m2;
        partML[base * 32 + l15 * 2 + 1] = lsum;
    }
}

// ---------------------------------------------------------------------------
// combine: grid (64, 16) x 64 thr. Merge <=4 partials per q-group (LSE merge),
// normalize, write fp32 out.
// ---------------------------------------------------------------------------
__global__ __launch_bounds__(64) void attn_comb_kernel(
    const float* __restrict__ partO, const float* __restrict__ partML,
    float* __restrict__ out)
{
    const int lane = threadIdx.x;
    const int l15 = lane & 15, lhi = lane >> 4;
    const int qw = blockIdx.x, b = blockIdx.y;
    const int nch = (qw >> 4) + 1;
    const size_t gbase = (size_t)(b * 64 + qw) * 4;

    float mc[4][4], lc[4][4];
    float M[4];
#pragma unroll
    for (int r = 0; r < 4; ++r) M[r] = -1e30f;
#pragma unroll
    for (int cc = 0; cc < 4; ++cc) {
        if (cc < nch) {
#pragma unroll
            for (int r = 0; r < 4; ++r) {
                const int row = lhi * 4 + r;
                mc[cc][r] = partML[(gbase + cc) * 32 + row * 2 + 0];
                lc[cc][r] = partML[(gbase + cc) * 32 + row * 2 + 1];
                M[r] = fmaxf(M[r], mc[cc][r]);
            }
        }
    }
    float sc[4][4], L[4];
#pragma unroll
    for (int r = 0; r < 4; ++r) L[r] = 0.f;
#pragma unroll
    for (int cc = 0; cc < 4; ++cc) {
        if (cc < nch) {
#pragma unroll
            for (int r = 0; r < 4; ++r) {
                sc[cc][r] = exp2f(mc[cc][r] - M[r]);
                L[r] += lc[cc][r] * sc[cc][r];
            }
        }
    }
    float linv[4];
#pragma unroll
    for (int r = 0; r < 4; ++r) linv[r] = 1.f / L[r];

#pragma unroll
    for (int nf = 0; nf < 4; ++nf) {
        float acc[4] = {0.f, 0.f, 0.f, 0.f};
#pragma unroll
        for (int cc = 0; cc < 4; ++cc) {
            if (cc < nch) {
                float4v v = *(const float4v*)(partO + (gbase + cc) * 1024
                                              + nf * 256 + lane * 4);
#pragma unroll
                for (int r = 0; r < 4; ++r) acc[r] += v[r] * sc[cc][r];
            }
        }
#pragma unroll
        for (int r = 0; r < 4; ++r) {
            const int row = qw * 16 + lhi * 4 + r;
            out[((size_t)(b * NT + row)) * NH + nf * 16 + l15] = acc[r] * linv[r];
        }
    }
}

extern "C" void kernel_launch(void* const* d_in, const int* in_sizes, int n_in,
                              void* d_out, int out_size, void* d_ws, size_t ws_size,
                              hipStream_t stream) {
    const float* x  = (const float*)d_in[0];
    const float* Wk = (const float*)d_in[1];
    const float* Wq = (const float*)d_in[2];
    const float* Wv = (const float*)d_in[3];

    _Float16* Qb = (_Float16*)d_ws;                        // 2 MB
    _Float16* Kb = Qb + (size_t)NB * NT * NH;              // 2 MB
    _Float16* Vt = Kb + (size_t)NB * NT * NH;              // 2 MB (transposed V)
    _Float16* Wt = Vt + (size_t)NB * NT * NH;              // 288 KB
    float* partO  = (float*)((char*)d_ws + (size_t)8  * 1024 * 1024);  // 16 MB
    float* partML = (float*)((char*)d_ws + (size_t)25 * 1024 * 1024);  // 512 KB

    wtrans_kernel<<<dim3(48, 3), dim3(256), 0, stream>>>(Wq, Wk, Wv, Wt);
    proj_kernel<<<dim3(512), dim3(256), 0, stream>>>(x, Wt, Qb, Kb, Vt);
    attn_part_kernel<<<dim3(40, 16), dim3(256), 0, stream>>>(Qb, Kb, Vt, partO, partML);
    attn_comb_kernel<<<dim3(64, 16), dim3(64), 0, stream>>>(partO, partML, (float*)d_out);
}

// Round 11
// 51.762 us; speedup vs baseline: 1.5798x; 1.2000x over previous
//
#include <hip/hip_runtime.h>

// SelfAttentionHead: B=16, T=1024, C=768, H=64, fp32 in/out, causal softmax.
// wtrans: W -> Wt[192][768] f16.
// proj:   R9 register-staged LDS GEMM, prefetch depth 2 (measured ~7-9 us, at
//         HBM floor).
// attn:   NEW block-cooperative split-KV flash: block = (64-row Q-tile, <=4 KV
//         tiles), 4 waves share double-buffered LDS K/V staged via
//         global_load_lds (linear dest + inverse-XOR-swizzled source);
//         in-register swapped-QK softmax; partials + LSE-combine.

typedef _Float16 half8 __attribute__((ext_vector_type(8)));
typedef _Float16 half4 __attribute__((ext_vector_type(4)));
typedef float float4v __attribute__((ext_vector_type(4)));

#define NB   16
#define NT   1024
#define NC   768
#define NH   64

typedef __attribute__((address_space(3))) unsigned int lds_u32_t;
typedef const __attribute__((address_space(1))) unsigned int g_u32_t;

__device__ __forceinline__ void gload16(const void* g, void* l) {
    __builtin_amdgcn_global_load_lds((g_u32_t*)g, (lds_u32_t*)l, 16, 0, 0);
}

// ---------------------------------------------------------------------------
// Wt[m*64+col][k] = Wm[k][col], m in {0:Q, 1:K, 2:V}. Grid (48,3) x 256.
// ---------------------------------------------------------------------------
__global__ __launch_bounds__(256) void wtrans_kernel(
    const float* __restrict__ Wq, const float* __restrict__ Wk,
    const float* __restrict__ Wv, _Float16* __restrict__ Wt)
{
    __shared__ float tile[16][68];
    const int m = blockIdx.y;
    const float* W = (m == 0) ? Wq : (m == 1) ? Wk : Wv;
    const int s = blockIdx.x;
    const int t = threadIdx.x;
    {
        const int kr = t >> 4, c4 = (t & 15) * 4;
        float4v v = *(const float4v*)(W + (size_t)(s * 16 + kr) * NH + c4);
        tile[kr][c4 + 0] = v[0]; tile[kr][c4 + 1] = v[1];
        tile[kr][c4 + 2] = v[2]; tile[kr][c4 + 3] = v[3];
    }
    __syncthreads();
    const int col = t >> 2, j = t & 3;
    half4 h;
#pragma unroll
    for (int i = 0; i < 4; ++i) h[i] = (_Float16)tile[j * 4 + i][col];
    *(half4*)(Wt + (size_t)(m * 64 + col) * NC + s * 16 + j * 4) = h;
}

// ---------------------------------------------------------------------------
// proj: grid 512 x 256 thr (4 waves). Block: 32 rows x 192 cols, BK=64.
// Register prefetch depth 2. (measured ~7-9 us — near HBM floor; unchanged)
// ---------------------------------------------------------------------------
__global__ __launch_bounds__(256) void proj_kernel(
    const float* __restrict__ x, const _Float16* __restrict__ Wt,
    _Float16* __restrict__ Qb, _Float16* __restrict__ Kb,
    _Float16* __restrict__ Vt)
{
    __shared__ _Float16 xl[32][68];

    const int t   = threadIdx.x;
    const int wid = t >> 6, lane = t & 63;
    const int l15 = lane & 15, lhi = lane >> 4;
    const int m0  = blockIdx.x * 32;
    const int srow = t >> 3, sc0 = (t & 7) * 8;

    const float*    xsrc  = x  + (size_t)(m0 + srow) * NC + sc0;
    const _Float16* wbase = Wt + (size_t)(wid * 48 + l15) * NC + lhi * 8;

    float4v acc[2][3];
#pragma unroll
    for (int i = 0; i < 2; ++i)
#pragma unroll
        for (int j = 0; j < 3; ++j)
            acc[i][j] = (float4v){0.f, 0.f, 0.f, 0.f};

    float4v g0[2], g1[2];
    half8 bf[2][3][2];
#pragma unroll
    for (int p = 0; p < 2; ++p) {
        g0[p] = *(const float4v*)(xsrc + p * 64);
        g1[p] = *(const float4v*)(xsrc + p * 64 + 4);
#pragma unroll
        for (int nf = 0; nf < 3; ++nf)
#pragma unroll
            for (int ks = 0; ks < 2; ++ks)
                bf[p][nf][ks] = *(const half8*)(wbase + (size_t)nf * 16 * NC
                                                + p * 64 + ks * 32);
    }

#pragma unroll 2
    for (int kc = 0; kc < 12; ++kc) {
        const int cur = kc & 1;
        __syncthreads();
        {
            half8 h;
            h[0] = (_Float16)g0[cur][0]; h[1] = (_Float16)g0[cur][1];
            h[2] = (_Float16)g0[cur][2]; h[3] = (_Float16)g0[cur][3];
            h[4] = (_Float16)g1[cur][0]; h[5] = (_Float16)g1[cur][1];
            h[6] = (_Float16)g1[cur][2]; h[7] = (_Float16)g1[cur][3];
            *(half8*)&xl[srow][sc0] = h;
        }
        __syncthreads();

        half8 bcur[3][2];
#pragma unroll
        for (int nf = 0; nf < 3; ++nf)
#pragma unroll
            for (int ks = 0; ks < 2; ++ks) bcur[nf][ks] = bf[cur][nf][ks];

        if (kc + 2 < 12) {
            g0[cur] = *(const float4v*)(xsrc + (kc + 2) * 64);
            g1[cur] = *(const float4v*)(xsrc + (kc + 2) * 64 + 4);
#pragma unroll
            for (int nf = 0; nf < 3; ++nf)
#pragma unroll
                for (int ks = 0; ks < 2; ++ks)
                    bf[cur][nf][ks] = *(const half8*)(wbase + (size_t)nf * 16 * NC
                                                      + (kc + 2) * 64 + ks * 32);
        }

        half8 af[2][2];
#pragma unroll
        for (int mf = 0; mf < 2; ++mf)
#pragma unroll
            for (int ks = 0; ks < 2; ++ks)
                af[mf][ks] = *(const half8*)&xl[mf * 16 + l15][ks * 32 + lhi * 8];

#pragma unroll
        for (int ks = 0; ks < 2; ++ks)
#pragma unroll
            for (int mf = 0; mf < 2; ++mf)
#pragma unroll
                for (int nf = 0; nf < 3; ++nf)
                    acc[mf][nf] = __builtin_amdgcn_mfma_f32_16x16x32_f16(
                        af[mf][ks], bcur[nf][ks], acc[mf][nf], 0, 0, 0);
    }

#pragma unroll
    for (int nf = 0; nf < 3; ++nf) {
        const int gc  = wid * 48 + nf * 16;
        const int sel = gc >> 6;
        const int col = (gc & 63) + l15;
#pragma unroll
        for (int mf = 0; mf < 2; ++mf) {
            const int row0 = m0 + mf * 16 + lhi * 4;
            if (sel == 2) {
                const int bb = row0 >> 10, tt = row0 & 1023;
                half4 h;
#pragma unroll
                for (int r = 0; r < 4; ++r) h[r] = (_Float16)acc[mf][nf][r];
                *(half4*)(Vt + ((size_t)(bb * 64 + col)) * NT + tt) = h;
            } else {
                _Float16* D = (sel == 0) ? Qb : Kb;
#pragma unroll
                for (int r = 0; r < 4; ++r)
                    D[(size_t)(row0 + r) * NH + col] = (_Float16)acc[mf][nf][r];
            }
        }
    }
}

// ---------------------------------------------------------------------------
// attn partial: grid (40, 16) x 256 thr (4 waves). Block i -> (qi, c):
// Q-tile qi (64 rows, wave wid owns rows qi*64+wid*16..+16), KV tiles
// [c*4, min(c*4+4, qi+1)). K/V staged to shared LDS (double buffer, swizzled
// global_load_lds). Writes unnormalized O + (m,l) partials at qw = qi*4+wid.
// ---------------------------------------------------------------------------
__global__ __launch_bounds__(256) void attn_part_kernel(
    const _Float16* __restrict__ Qb, const _Float16* __restrict__ Kb,
    const _Float16* __restrict__ Vt, float* __restrict__ partO,
    float* __restrict__ partML)
{
    __shared__ _Float16 Kl[2][64 * 64];   // [buf][row*64 + swzchunk*8], 8 KB each
    __shared__ _Float16 Vl[2][64 * 64];

    const int tid = threadIdx.x;
    const int lane = tid & 63, w = tid >> 6;
    const int l15 = lane & 15, lhi = lane >> 4;
    const int b = blockIdx.y;
    const int i = blockIdx.x;
    int qi, c;
    if (i < 4)       { qi = i;                 c = 0; }
    else if (i < 12) { int j = i - 4;  qi = 4 + (j >> 1); c = j & 1; }
    else if (i < 24) { int j = i - 12; qi = 8 + j / 3;    c = j - 3 * (j / 3); }
    else             { int j = i - 24; qi = 12 + (j >> 2); c = j & 3; }

    const int nt = qi + 1;
    const int t0 = c * 4;
    const int t1 = min(t0 + 4, nt);
    const int q0 = qi * 64;
    const int qrel = w * 16 + l15;     // q within the 64-row tile (mask ref)

    // Q fragment (B-operand of swapped QK^T)
    const _Float16* qsrc = Qb + ((size_t)(b * NT + q0 + w * 16 + l15)) * NH + lhi * 8;
    const half8 aq0 = *(const half8*)qsrc;
    const half8 aq1 = *(const half8*)(qsrc + 32);

    // staging geometry: slot s in [0,512): row = s>>3, chunk c8 = s&7;
    // LDS slot (row,c8) holds global 16B chunk (c8 ^ (row&7)).
    const int s1 = w * 64 + lane, s2 = 256 + w * 64 + lane;
    const int r1 = s1 >> 3, c1 = (s1 & 7) ^ (r1 & 7);
    const int r2 = s2 >> 3, c2 = (s2 & 7) ^ (r2 & 7);
    const _Float16* ksrc1 = Kb + ((size_t)(b * NT + r1)) * NH + c1 * 8;
    const _Float16* ksrc2 = Kb + ((size_t)(b * NT + r2)) * NH + c2 * 8;
    const _Float16* vsrc1 = Vt + ((size_t)(b * 64 + r1)) * NT + c1 * 8;
    const _Float16* vsrc2 = Vt + ((size_t)(b * 64 + r2)) * NT + c2 * 8;

    auto STAGE = [&](int jt, int buf) {
        gload16(ksrc1 + (size_t)jt * 64 * NH, &Kl[buf][(size_t)(w * 64) * 8]);
        gload16(ksrc2 + (size_t)jt * 64 * NH, &Kl[buf][(size_t)(256 + w * 64) * 8]);
        gload16(vsrc1 + jt * 64, &Vl[buf][(size_t)(w * 64) * 8]);
        gload16(vsrc2 + jt * 64, &Vl[buf][(size_t)(256 + w * 64) * 8]);
    };

    float4v o[4];
#pragma unroll
    for (int nf = 0; nf < 4; ++nf) o[nf] = (float4v){0.f, 0.f, 0.f, 0.f};
    float m2 = -1e30f, lsum = 0.f;

    STAGE(t0, 0);
    asm volatile("s_waitcnt vmcnt(0)" ::: "memory");
    __syncthreads();

    for (int jt = t0; jt < t1; ++jt) {
        const int buf = (jt - t0) & 1;
        const bool last = (jt == nt - 1);
        if (jt + 1 < t1) STAGE(jt + 1, buf ^ 1);

        // S^T = K * Q^T from LDS (swizzled ds_read_b128, conflict-free)
        float4v sT[4];
#pragma unroll
        for (int kf = 0; kf < 4; ++kf) {
            const int row = kf * 16 + l15;
            const int sw = row & 7;
            half8 bk0 = *(const half8*)&Kl[buf][row * 64 + ((lhi     ^ sw) * 8)];
            half8 bk1 = *(const half8*)&Kl[buf][row * 64 + (((4+lhi) ^ sw) * 8)];
            float4v sv = (float4v){0.f, 0.f, 0.f, 0.f};
            sv = __builtin_amdgcn_mfma_f32_16x16x32_f16(bk0, aq0, sv, 0, 0, 0);
            sv = __builtin_amdgcn_mfma_f32_16x16x32_f16(bk1, aq1, sv, 0, 0, 0);
            sT[kf] = sv;
        }

        const float SC = 0.18033688f;   // 0.125 * log2(e)
        float p[4][4];
        float mt = -1e30f;
#pragma unroll
        for (int kf = 0; kf < 4; ++kf)
#pragma unroll
            for (int r = 0; r < 4; ++r) {
                float v = sT[kf][r] * SC;
                if (last) {
                    const int kpos = kf * 16 + lhi * 4 + r;
                    if (kpos > qrel) v = -1e30f;
                }
                p[kf][r] = v;
                mt = fmaxf(mt, v);
            }
        mt = fmaxf(mt, __shfl_xor(mt, 16));
        mt = fmaxf(mt, __shfl_xor(mt, 32));

        const float mnew = fmaxf(m2, mt);
        const float esc  = exp2f(m2 - mnew);
        float ps = 0.f;
#pragma unroll
        for (int kf = 0; kf < 4; ++kf)
#pragma unroll
            for (int r = 0; r < 4; ++r) {
                const float e = exp2f(p[kf][r] - mnew);
                p[kf][r] = e;
                ps += e;
            }
        ps += __shfl_xor(ps, 16);
        ps += __shfl_xor(ps, 32);
        lsum = lsum * esc + ps;
        m2 = mnew;

        float er[4];
#pragma unroll
        for (int r = 0; r < 4; ++r) er[r] = __shfl(esc, lhi * 4 + r);
#pragma unroll
        for (int nf = 0; nf < 4; ++nf)
#pragma unroll
            for (int r = 0; r < 4; ++r) o[nf][r] *= er[r];

        unsigned int pk[4][2];
#pragma unroll
        for (int kf = 0; kf < 4; ++kf)
#pragma unroll
            for (int pr = 0; pr < 2; ++pr) {
                auto h2 = __builtin_amdgcn_cvt_pkrtz(p[kf][2 * pr], p[kf][2 * pr + 1]);
                pk[kf][pr] = __builtin_bit_cast(unsigned int, h2);
            }

        const int sb = l15 + ((lhi & 1) * 2) * 16;
        const bool hi = (lhi >> 1) != 0;
#pragma unroll
        for (int ks = 0; ks < 2; ++ks) {
            unsigned int wv[4];
#pragma unroll
            for (int m = 0; m < 4; ++m) {
                const int L = sb + ((m >> 1) << 4);
                const unsigned int wA = (unsigned int)__shfl((int)pk[2 * ks + 0][m & 1], L);
                const unsigned int wB = (unsigned int)__shfl((int)pk[2 * ks + 1][m & 1], L);
                wv[m] = hi ? wB : wA;
            }
            union { unsigned int u[4]; half8 h; } cvt;
            cvt.u[0] = wv[0]; cvt.u[1] = wv[1]; cvt.u[2] = wv[2]; cvt.u[3] = wv[3];
            const half8 pa = cvt.h;
#pragma unroll
            for (int nf = 0; nf < 4; ++nf) {
                const int row = nf * 16 + l15;
                const half8 bvv = *(const half8*)&Vl[buf][row * 64
                                    + (((ks * 4 + lhi) ^ (row & 7)) * 8)];
                o[nf] = __builtin_amdgcn_mfma_f32_16x16x32_f16(pa, bvv, o[nf], 0, 0, 0);
            }
        }

        asm volatile("s_waitcnt vmcnt(0)" ::: "memory");  // own stage(jt+1) done
        __syncthreads();                                  // all reads of buf done
    }

    const size_t base = (size_t)((b * 64 + qi * 4 + w) * 4 + c);
#pragma unroll
    for (int nf = 0; nf < 4; ++nf) {
        float4v v = o[nf];
        *(float4v*)(partO + (base * 4 + nf) * 256 + lane * 4) = v;
    }
    if (lhi == 0) {
        partML[base * 32 + l15 * 2 + 0] = m2;
        partML[base * 32 + l15 * 2 + 1] = lsum;
    }
}

// ---------------------------------------------------------------------------
// combine: grid (64, 16) x 64 thr. Merge <=4 partials per q-group (LSE merge),
// normalize, write fp32 out.
// ---------------------------------------------------------------------------
__global__ __launch_bounds__(64) void attn_comb_kernel(
    const float* __restrict__ partO, const float* __restrict__ partML,
    float* __restrict__ out)
{
    const int lane = threadIdx.x;
    const int l15 = lane & 15, lhi = lane >> 4;
    const int qw = blockIdx.x, b = blockIdx.y;
    const int nch = (qw >> 4) + 1;
    const size_t gbase = (size_t)(b * 64 + qw) * 4;

    float mc[4][4], lc[4][4];
    float M[4];
#pragma unroll
    for (int r = 0; r < 4; ++r) M[r] = -1e30f;
#pragma unroll
    for (int cc = 0; cc < 4; ++cc) {
        if (cc < nch) {
#pragma unroll
            for (int r = 0; r < 4; ++r) {
                const int row = lhi * 4 + r;
                mc[cc][r] = partML[(gbase + cc) * 32 + row * 2 + 0];
                lc[cc][r] = partML[(gbase + cc) * 32 + row * 2 + 1];
                M[r] = fmaxf(M[r], mc[cc][r]);
            }
        }
    }
    float sc[4][4], L[4];
#pragma unroll
    for (int r = 0; r < 4; ++r) L[r] = 0.f;
#pragma unroll
    for (int cc = 0; cc < 4; ++cc) {
        if (cc < nch) {
#pragma unroll
            for (int r = 0; r < 4; ++r) {
                sc[cc][r] = exp2f(mc[cc][r] - M[r]);
                L[r] += lc[cc][r] * sc[cc][r];
            }
        }
    }
    float linv[4];
#pragma unroll
    for (int r = 0; r < 4; ++r) linv[r] = 1.f / L[r];

#pragma unroll
    for (int nf = 0; nf < 4; ++nf) {
        float acc[4] = {0.f, 0.f, 0.f, 0.f};
#pragma unroll
        for (int cc = 0; cc < 4; ++cc) {
            if (cc < nch) {
                float4v v = *(const float4v*)(partO + (gbase + cc) * 1024
                                              + nf * 256 + lane * 4);
#pragma unroll
                for (int r = 0; r < 4; ++r) acc[r] += v[r] * sc[cc][r];
            }
        }
#pragma unroll
        for (int r = 0; r < 4; ++r) {
            const int row = qw * 16 + lhi * 4 + r;
            out[((size_t)(b * NT + row)) * NH + nf * 16 + l15] = acc[r] * linv[r];
        }
    }
}

extern "C" void kernel_launch(void* const* d_in, const int* in_sizes, int n_in,
                              void* d_out, int out_size, void* d_ws, size_t ws_size,
                              hipStream_t stream) {
    const float* x  = (const float*)d_in[0];
    const float* Wk = (const float*)d_in[1];
    const float* Wq = (const float*)d_in[2];
    const float* Wv = (const float*)d_in[3];

    _Float16* Qb = (_Float16*)d_ws;                        // 2 MB
    _Float16* Kb = Qb + (size_t)NB * NT * NH;              // 2 MB
    _Float16* Vt = Kb + (size_t)NB * NT * NH;              // 2 MB (transposed V)
    _Float16* Wt = Vt + (size_t)NB * NT * NH;              // 288 KB
    float* partO  = (float*)((char*)d_ws + (size_t)8  * 1024 * 1024);  // 17 MB
    float* partML = (float*)((char*)d_ws + (size_t)25 * 1024 * 1024);  // 512 KB

    wtrans_kernel<<<dim3(48, 3), dim3(256), 0, stream>>>(Wq, Wk, Wv, Wt);
    proj_kernel<<<dim3(512), dim3(256), 0, stream>>>(x, Wt, Qb, Kb, Vt);
    attn_part_kernel<<<dim3(40, 16), dim3(256), 0, stream>>>(Qb, Kb, Vt, partO, partML);
    attn_comb_kernel<<<dim3(64, 16), dim3(64), 0, stream>>>(partO, partML, (float*)d_out);
}